// Round 20
// baseline (293.194 us; speedup 1.0000x reference)
//
#include <hip/hip_runtime.h>
#include <hip/hip_bf16.h>

// ---------------- problem constants ----------------
#define BATCH  4
#define NTOK   12281
#define DIMIN  512
#define HEADS  8
#define DHEAD  64
#define MPATH  281
#define NHIST  12000               // NTOK - MPATH
#define QKVC   1536                // 3 * HEADS * DHEAD
#define QSCALE 0.180336884f        // DHEAD^-0.5 * log2(e)  (softmax uses exp2)
#define ROWS   (BATCH * NTOK)      // 49124
#define MPAD   49152               // 384 * 128 (padded GEMM M)
#define NSPLIT 16
#define KSPL   768                 // 24 tiles; splits 0-14 full, split 15 = 480 (15 tiles)
#define PROWS  320                 // padded path rows  (10 tiles of 32)
#define HROWS  12032               // padded hist rows  (376 tiles of 32)
#define M1B    640                 // MODE-1 blocks: 8 xcd x 80 (2 sp x 32 bh x 5 pw / 4)
#define M0B    1504                // MODE-0 blocks: 8 xcd x 4 g x 47
#define QPAD   4096                // qb tail pad (MODE0 set-B over-read, bh=31)
#define NB_CONV 12288              // MPAD*DIMIN/8/256
#define NB_WT   192                // (DIMIN/64)*(QKVC/64)
#define NB_PAD  312

typedef __attribute__((ext_vector_type(8)))  short        short8v;  // 8 bf16
typedef __attribute__((ext_vector_type(4)))  float        f32x4;
typedef __attribute__((ext_vector_type(16))) float        f32x16;
typedef __attribute__((ext_vector_type(4)))  unsigned int uint4v;

__device__ __forceinline__ unsigned short f2bf(float f) {          // RNE float->bf16
    unsigned x = __builtin_bit_cast(unsigned, f);
    return (unsigned short)((x + 0x7fffu + ((x >> 16) & 1u)) >> 16);
}
__device__ __forceinline__ unsigned pk2(float a, float b) {
    return (unsigned)f2bf(a) | ((unsigned)f2bf(b) << 16);
}
__device__ __forceinline__ unsigned pk2n(float a, float b) {       // native v_cvt_pk_bf16_f32
    unsigned r;
    asm("v_cvt_pk_bf16_f32 %0, %1, %2" : "=v"(r) : "v"(a), "v"(b));
    return r;
}
// v_permlane32_swap_b32: after, a = {a.lo, b.lo}, b = {a.hi, b.hi}
__device__ __forceinline__ void plswap(unsigned &a, unsigned &b) {
    asm("v_permlane32_swap_b32 %0, %1" : "+v"(a), "+v"(b));
}
__device__ __forceinline__ float fexp2(float x) {                  // v_exp_f32 (2^x)
    return __builtin_amdgcn_exp2f(x);
}
__device__ __forceinline__ short8v ld8(const unsigned short* p) {
    return *reinterpret_cast<const short8v*>(p);
}
__device__ __forceinline__ f32x16 MFMA32(short8v a, short8v b, f32x16 c) {
    return __builtin_amdgcn_mfma_f32_32x32x16_bf16(a, b, c, 0, 0, 0);
}
__device__ __forceinline__ void gl16(const char* g, char* l) {     // 16B global->LDS DMA
    __builtin_amdgcn_global_load_lds(
        (const __attribute__((address_space(1))) unsigned int*)g,
        (__attribute__((address_space(3))) unsigned int*)l, 16, 0, 0);
}

// ---------------- kernel P: merged prep (x->bf16, W->Wt bf16, pad zeroing)
// Pad zeroing now targets K rows (row-major) and V^T pad tiles directly
// (GEMM writes V^T in its epilogue; no transpose kernel).
__global__ __launch_bounds__(256)
void prep_all(const float* __restrict__ x, unsigned short* __restrict__ xb,
              const float* __restrict__ w, unsigned short* __restrict__ wt,
              unsigned short* kpth, unsigned short* khst,
              unsigned short* vtp,  unsigned short* vth)
{
    __shared__ unsigned short Ls[64][72];
    const int b   = blockIdx.x;
    const int tid = threadIdx.x;

    if (b < NB_CONV) {
        // ---- convert_x: fp32 -> bf16, rows padded to MPAD with zeros
        size_t i = ((size_t)b * 256 + tid) * 8;
        uint4v o;
        if (i < (size_t)ROWS * DIMIN) {
            float4 a = *reinterpret_cast<const float4*>(x + i);
            float4 c = *reinterpret_cast<const float4*>(x + i + 4);
            o[0] = pk2(a.x, a.y); o[1] = pk2(a.z, a.w);
            o[2] = pk2(c.x, c.y); o[3] = pk2(c.z, c.w);
        } else {
            o[0] = o[1] = o[2] = o[3] = 0u;
        }
        *reinterpret_cast<uint4v*>(xb + i) = o;
    } else if (b < NB_CONV + NB_WT) {
        // ---- wt_convert: W[512][1536] fp32 -> Wt[1536][512] bf16
        const int bb = b - NB_CONV;
        const int k0 = (bb & 7) * 64;
        const int n0 = (bb >> 3) * 64;
        const int lr = tid >> 2;
        const int c0 = (tid & 3) * 16;

        const float* sp = w + (size_t)(k0 + lr) * QKVC + n0 + c0;
        #pragma unroll
        for (int j = 0; j < 16; j += 4) {
            float4 a = *reinterpret_cast<const float4*>(sp + j);
            Ls[lr][c0 + j + 0] = f2bf(a.x);
            Ls[lr][c0 + j + 1] = f2bf(a.y);
            Ls[lr][c0 + j + 2] = f2bf(a.z);
            Ls[lr][c0 + j + 3] = f2bf(a.w);
        }
        __syncthreads();

        alignas(16) unsigned short tmp[16];
        #pragma unroll
        for (int j = 0; j < 16; ++j) tmp[j] = Ls[c0 + j][lr];
        unsigned short* dp = wt + (size_t)(n0 + lr) * DIMIN + k0 + c0;
        *reinterpret_cast<short8v*>(dp)     = *reinterpret_cast<short8v*>(&tmp[0]);
        *reinterpret_cast<short8v*>(dp + 8) = *reinterpret_cast<short8v*>(&tmp[8]);
    } else {
        // ---- pad zeroing
        const int i = (b - NB_CONV - NB_WT) * 256 + tid;
        const int PPAD = (PROWS - MPATH) * DHEAD;     // 2496 per bh
        const int HPAD = (HROWS - NHIST) * DHEAD;     // 2048 per bh
        if (i < 32 * PPAD) {
            const int bh = i / PPAD, r = i - bh * PPAD;
            // K path rows (row-major)
            kpth[((size_t)bh * PROWS + MPATH) * DHEAD + r] = 0;
            // V^T path pad: tok = MPATH + r/64, d = r%64
            const int tok = MPATH + (r >> 6);
            const int d   = r & 63;
            vtp[(size_t)bh * PROWS * DHEAD + (((tok >> 5) * 64 + d) << 5) + (tok & 31)] = 0;
        }
        if (i < 32 * HPAD) {
            const int bh = i / HPAD, r = i - bh * HPAD;
            khst[((size_t)bh * HROWS + NHIST) * DHEAD + r] = 0;
            const int tok = NHIST + (r >> 6);       // 12000 % 32 == 0 -> tile 375
            const int d   = r & 63;
            vth[(size_t)bh * HROWS * DHEAD + (((tok >> 5) * 64 + d) << 5) + (tok & 31)] = 0;
        }
    }
}

// =====================================================================
// kernel 1: bf16 MFMA QKV GEMM. 128x128 tile, BK=64, 4 waves (2x2 of 64x64).
// Single 32KB stage buffer (m97 structure); epilogue reuses 34KB LDS.
// V columns are written DIRECTLY in tile-blocked V^T layout (8x2B scatter
// per chunk, stays within one 4KB V^T tile -> L2 absorbs; transpose kernel
// eliminated).
// =====================================================================
__global__ __launch_bounds__(256, 4)
void qkv_mfma(const unsigned short* __restrict__ xb, const unsigned short* __restrict__ wt,
              unsigned short* __restrict__ qb,
              unsigned short* __restrict__ kpth, unsigned short* __restrict__ khst,
              unsigned short* __restrict__ vtp,  unsigned short* __restrict__ vth)
{
    __shared__ char lds[34816];        // 32KB stage (16KB A + 16KB B) / 34KB epilogue
    const int tid  = threadIdx.x;
    const int lane = tid & 63;
    const int wid  = tid >> 6;
    const int wr   = wid >> 1;
    const int wc   = wid & 1;

    int id  = blockIdx.x;
    int wg  = (id & 7) * 576 + (id >> 3);
    const int mt = wg / 12, nt = wg - mt * 12;
    const int bm = mt * 128, bn = nt * 128;

    const int arow0 = tid >> 3;
    const int acolS = ((tid & 7) << 4) ^ ((arow0 & 7) << 4);
    const char* xsrc = (const char*)xb + (((size_t)(bm + arow0)) << 10) + acolS;
    const char* wsrc = (const char*)wt + (((size_t)(bn + arow0)) << 10) + acolS;
    char* ldsA = lds + wid * 1024;
    char* ldsB = lds + 16384 + wid * 1024;

    const int rA   = wr * 64 + (lane & 15);
    const int rB   = wc * 64 + (lane & 15);
    const int hi16 = (lane >> 4) << 4;
    const int sxA  = (rA & 7) << 4;
    const int sxB  = (rB & 7) << 4;

    f32x4 acc[4][4];
    #pragma unroll
    for (int m = 0; m < 4; ++m)
        #pragma unroll
        for (int n = 0; n < 4; ++n)
            #pragma unroll
            for (int r = 0; r < 4; ++r) acc[m][n][r] = 0.f;

    auto STAGE = [&](int ks) {
        const char* xs = xsrc + (size_t)ks * 128;
        const char* ws = wsrc + (size_t)ks * 128;
        #pragma unroll
        for (int i = 0; i < 4; ++i)
            gl16(xs + ((size_t)i << 15), ldsA + i * 4096);
        #pragma unroll
        for (int i = 0; i < 4; ++i)
            gl16(ws + ((size_t)i << 15), ldsB + i * 4096);
    };

    STAGE(0);
    asm volatile("s_waitcnt vmcnt(0)" ::: "memory");
    __syncthreads();

    for (int ks = 0; ks < 8; ++ks) {
        const char* A = lds;
        const char* B = A + 16384;
        #pragma unroll
        for (int kk = 0; kk < 2; ++kk) {
            short8v a[4], b[4];
            #pragma unroll
            for (int m = 0; m < 4; ++m)
                a[m] = *reinterpret_cast<const short8v*>(
                    A + (rA + m * 16) * 128 + ((kk * 64 + hi16) ^ sxA));
            #pragma unroll
            for (int n = 0; n < 4; ++n)
                b[n] = *reinterpret_cast<const short8v*>(
                    B + (rB + n * 16) * 128 + ((kk * 64 + hi16) ^ sxB));
            #pragma unroll
            for (int m = 0; m < 4; ++m)
                #pragma unroll
                for (int n = 0; n < 4; ++n)
                    acc[m][n] = __builtin_amdgcn_mfma_f32_16x16x32_bf16(
                        a[m], b[n], acc[m][n], 0, 0, 0);
        }
        __syncthreads();                 // all waves done reading the buffer
        if (ks < 7) {
            STAGE(ks + 1);
            asm volatile("s_waitcnt vmcnt(0)" ::: "memory");
            __syncthreads();
        }
    }

    unsigned short* cl = reinterpret_cast<unsigned short*>(lds);
    const int crow0 = (lane >> 4) * 4;
    const int ccol  = lane & 15;
    #pragma unroll
    for (int n = 0; n < 4; ++n) {
        const int gcb = bn + wc * 64 + n * 16;
        const float scl = (gcb < 512) ? QSCALE : 1.f;
        #pragma unroll
        for (int m = 0; m < 4; ++m) {
            #pragma unroll
            for (int r = 0; r < 4; ++r) {
                int row = wr * 64 + m * 16 + crow0 + r;
                int col = wc * 64 + n * 16 + ccol;
                cl[row * 136 + col] = f2bf(acc[m][n][r] * scl);
            }
        }
    }
    __syncthreads();

    #pragma unroll
    for (int i = 0; i < 8; ++i) {
        const int chunk = tid + i * 256;
        const int row = chunk >> 4;
        const int c8  = (chunk & 15) * 8;
        const int grow = bm + row;
        if (grow < ROWS) {
            uint4v val = *reinterpret_cast<const uint4v*>(cl + row * 136 + c8);
            const int gcol  = bn + c8;
            const int which = gcol >> 9;
            const int rem   = gcol & 511;
            const int hh = rem >> 6, dd = rem & 63;
            const int bb = grow / NTOK;
            const int nn = grow - bb * NTOK;
            const int bh = bb * HEADS + hh;
            if (which == 0) {
                *reinterpret_cast<uint4v*>(
                    qb + ((size_t)bh * NTOK + nn) * DHEAD + dd) = val;
            } else if (which == 1) {
                unsigned short* dst =
                    (nn < MPATH) ? kpth + ((size_t)bh * PROWS + nn) * DHEAD + dd
                                 : khst + ((size_t)bh * HROWS + (nn - MPATH)) * DHEAD + dd;
                *reinterpret_cast<uint4v*>(dst) = val;
            } else {
                // V: direct tile-blocked V^T scatter  [bh][tok/32][d][tok%32]
                unsigned short* vdst;
                int tok;
                if (nn < MPATH) {
                    tok  = nn;
                    vdst = vtp + (size_t)bh * PROWS * DHEAD;
                } else {
                    tok  = nn - MPATH;
                    vdst = vth + (size_t)bh * HROWS * DHEAD;
                }
                vdst += (((tok >> 5) * 64 + dd) << 5) + (tok & 31);
                #pragma unroll
                for (int j = 0; j < 4; ++j) {
                    const unsigned u = val[j];
                    vdst[(2 * j) * 32]     = (unsigned short)(u & 0xffffu);
                    vdst[(2 * j + 1) * 32] = (unsigned short)(u >> 16);
                }
            }
        }
    }
}

// ---- attention tile body (r16/r19 configuration: the ~120us best).
// VC* = V(t) (consumed); VN* = V(t+1) prefetch AFTER PV; K reload after QK.
#define ATTN_BODY(VC0,VC1,VC2,VC3,VN0,VN1,VN2,VN3,TT)                      \
  do {                                                                     \
    __builtin_amdgcn_s_setprio(1);                                         \
    f32x16 sA = MFMA32(kf0, qA0, SZ);                                      \
    sA = MFMA32(kf1, qA1, sA);                                             \
    sA = MFMA32(kf2, qA2, sA);                                             \
    sA = MFMA32(kf3, qA3, sA);                                             \
    f32x16 sB = MFMA32(kf0, qB0, SZ);                                      \
    sB = MFMA32(kf1, qB1, sB);                                             \
    sB = MFMA32(kf2, qB2, sB);                                             \
    sB = MFMA32(kf3, qB3, sB);                                             \
    __builtin_amdgcn_s_setprio(0);                                         \
    if ((TT) + 1 < ntiles) {   /* K(t+1) reload after QK consumed kf */    \
      const unsigned short* kn = kr + (size_t)((TT) + 1) * 2048;           \
      kf0 = ld8(kn);      kf1 = ld8(kn + 16);                              \
      kf2 = ld8(kn + 32); kf3 = ld8(kn + 48);                              \
    }                                                                      \
    float psA = 0.f, psB = 0.f;                                            \
    if (mode0 && (TT) == 8) {          /* mask path keys >= 281 */         \
      _Pragma("unroll")                                                    \
      for (int r = 0; r < 16; ++r) {                                       \
        int krow = (r & 3) + 8 * (r >> 2) + 4 * hi;                        \
        float eA = (256 + krow >= MPATH) ? 0.f : fexp2(sA[r]);             \
        float eB = (256 + krow >= MPATH) ? 0.f : fexp2(sB[r]);             \
        sA[r] = eA; psA += eA;                                             \
        sB[r] = eB; psB += eB;                                             \
      }                                                                    \
    } else {                                                               \
      _Pragma("unroll")                                                    \
      for (int r = 0; r < 16; ++r) {                                       \
        float eA = fexp2(sA[r]); sA[r] = eA; psA += eA;                    \
        float eB = fexp2(sB[r]); sB[r] = eB; psB += eB;                    \
      }                                                                    \
    }                                                                      \
    lA += psA; lB += psB;                                                  \
    unsigned A0 = pk2n(sA[0],  sA[1]),  A1 = pk2n(sA[2],  sA[3]);          \
    unsigned A2 = pk2n(sA[4],  sA[5]),  A3 = pk2n(sA[6],  sA[7]);          \
    unsigned A4 = pk2n(sA[8],  sA[9]),  A5 = pk2n(sA[10], sA[11]);         \
    unsigned A6 = pk2n(sA[12], sA[13]), A7 = pk2n(sA[14], sA[15]);         \
    plswap(A0, A2); plswap(A1, A3); plswap(A4, A6); plswap(A5, A7);        \
    uint4v wA0, wA1;                                                       \
    wA0[0] = A0; wA0[1] = A1; wA0[2] = A2; wA0[3] = A3;                    \
    wA1[0] = A4; wA1[1] = A5; wA1[2] = A6; wA1[3] = A7;                    \
    short8v paA0 = __builtin_bit_cast(short8v, wA0);                       \
    short8v paA1 = __builtin_bit_cast(short8v, wA1);                       \
    unsigned B0 = pk2n(sB[0],  sB[1]),  B1 = pk2n(sB[2],  sB[3]);          \
    unsigned B2 = pk2n(sB[4],  sB[5]),  B3 = pk2n(sB[6],  sB[7]);          \
    unsigned B4 = pk2n(sB[8],  sB[9]),  B5 = pk2n(sB[10], sB[11]);         \
    unsigned B6 = pk2n(sB[12], sB[13]), B7 = pk2n(sB[14], sB[15]);         \
    plswap(B0, B2); plswap(B1, B3); plswap(B4, B6); plswap(B5, B7);        \
    uint4v wB0, wB1;                                                       \
    wB0[0] = B0; wB0[1] = B1; wB0[2] = B2; wB0[3] = B3;                    \
    wB1[0] = B4; wB1[1] = B5; wB1[2] = B6; wB1[3] = B7;                    \
    short8v paB0 = __builtin_bit_cast(short8v, wB0);                       \
    short8v paB1 = __builtin_bit_cast(short8v, wB1);                       \
    __builtin_amdgcn_s_setprio(1);                                         \
    o0 = MFMA32(paA0, VC0, o0);                                            \
    o0 = MFMA32(paA1, VC1, o0);                                            \
    o1 = MFMA32(paA0, VC2, o1);                                            \
    o1 = MFMA32(paA1, VC3, o1);                                            \
    o2 = MFMA32(paB0, VC0, o2);                                            \
    o2 = MFMA32(paB1, VC1, o2);                                            \
    o3 = MFMA32(paB0, VC2, o3);                                            \
    o3 = MFMA32(paB1, VC3, o3);                                            \
    __builtin_amdgcn_s_setprio(0);                                         \
    if ((TT) + 1 < ntiles) {   /* load V(t+1) */                           \
      const unsigned short* vn = vbase + (size_t)((TT) + 1) * 2048;        \
      VN0 = ld8(vn);        VN1 = ld8(vn + 16);                            \
      VN2 = ld8(vn + 1024); VN3 = ld8(vn + 1040);                          \
    }                                                                      \
  } while (0)

// =====================================================================
// kernel 3: FUSED MFMA flash attention, 64 queries/wave (two S-tiles per
// K/V load set), K(t+1) AND V(t+1) register-prefetched a full tile ahead.
// Blocks [0, M1B):       MODE 1 (path q x hist k), XCD-pinned by sp%8
// Blocks [M1B, M1B+M0B): MODE 0 (hist q x path k), XCD-pinned by bh group
// =====================================================================
__global__ __launch_bounds__(256, 2)
void fused_attn(const unsigned short* __restrict__ qbuf,
                const unsigned short* __restrict__ kpth, const unsigned short* __restrict__ khst,
                const unsigned short* __restrict__ vtp,  const unsigned short* __restrict__ vth,
                float* __restrict__ out,
                float* __restrict__ pl, float* __restrict__ po)
{
    const int wave = threadIdx.x >> 6;
    const int lane = threadIdx.x & 63;
    const int hi   = lane >> 5;
    const int ql   = lane & 31;

    int bh, pw, sp = 0;
    bool mode0;
    if (blockIdx.x < M1B) {
        mode0 = false;
        const int xcd = blockIdx.x & 7;
        const int j   = blockIdx.x >> 3;         // 0..79
        const int w   = j * 4 + wave;            // 0..319
        const int spi = w / 160;                 // 0..1
        const int rem = w - spi * 160;
        bh = rem / 5;                            // 0..31
        pw = rem - bh * 5;                       // 0..4
        sp = xcd + 8 * spi;                      // pinned to xcd mod 8
    } else {
        mode0 = true;
        const int b0  = blockIdx.x - M1B;
        const int xcd = b0 & 7;
        const int i   = b0 >> 3;                 // 0..187
        const int g   = i / 47;                  // 0..3
        bh = xcd + 8 * g;
        pw = (i - g * 47) * 4 + wave;            // 0..187 (exactly covered)
    }

    const int q0 = mode0 ? (MPATH + pw * 64) : (pw * 64);
    const unsigned short* qra = qbuf + ((size_t)bh * NTOK + (q0 + ql)) * DHEAD + hi * 8;
    const unsigned short* qrb = qra + (size_t)32 * DHEAD;
    short8v qA0 = ld8(qra),      qA1 = ld8(qra + 16);
    short8v qA2 = ld8(qra + 32), qA3 = ld8(qra + 48);
    short8v qB0 = ld8(qrb),      qB1 = ld8(qrb + 16);
    short8v qB2 = ld8(qrb + 32), qB3 = ld8(qrb + 48);

    const unsigned short* kr;        // lane-adjusted K base (tile stride 2048)
    const unsigned short* vbase;     // lane-adjusted tile-blocked V^T base
    int ntiles;
    if (mode0) {
        kr    = kpth + (size_t)bh * PROWS * DHEAD + ql * DHEAD + hi * 8;
        vbase = vtp  + (size_t)bh * PROWS * DHEAD + ql * 32 + hi * 8;
        ntiles = 9;
    } else {
        kr    = khst + ((size_t)bh * HROWS + (size_t)sp * KSPL) * DHEAD + ql * DHEAD + hi * 8;
        vbase = vth  + (size_t)bh * HROWS * DHEAD + (size_t)sp * 24 * 2048 + ql * 32 + hi * 8;
        ntiles = (sp == NSPLIT - 1) ? 15 : 24;   // split 15: 480 keys exactly
    }

    f32x16 o0, o1, o2, o3, SZ;
    #pragma unroll
    for (int r = 0; r < 16; ++r) { o0[r] = 0.f; o1[r] = 0.f; o2[r] = 0.f; o3[r] = 0.f; SZ[r] = 0.f; }
    float lA = 0.f, lB = 0.f;

    // prologue: K(0), V(0)
    short8v kf0 = ld8(kr), kf1 = ld8(kr + 16), kf2 = ld8(kr + 32), kf3 = ld8(kr + 48);
    short8v va0 = ld8(vbase),        va1 = ld8(vbase + 16);
    short8v va2 = ld8(vbase + 1024), va3 = ld8(vbase + 1040);
    short8v vb0 = va0, vb1 = va1, vb2 = va2, vb3 = va3;   // init (dead unless rotated)

    for (int t = 0;;) {
        ATTN_BODY(va0, va1, va2, va3, vb0, vb1, vb2, vb3, t);
        if (++t >= ntiles) break;
        ATTN_BODY(vb0, vb1, vb2, vb3, va0, va1, va2, va3, t);
        if (++t >= ntiles) break;
    }

    const float lAr = lA + __shfl_xor(lA, 32);
    const float lBr = lB + __shfl_xor(lB, 32);

    if (mode0) {
        const int bb = bh >> 3, hh = bh & 7;
        const float liA = 1.0f / lAr;
        const float liB = 1.0f / lBr;
        #pragma unroll
        for (int r = 0; r < 16; ++r) {
            const int row = (r & 3) + 8 * (r >> 2) + 4 * hi;
            {
                float invr = __shfl(liA, row);
                float* op = out + ((size_t)bb * NTOK + (pw * 64 + row)) * (HEADS * DHEAD) + hh * DHEAD;
                op[ql]      = o0[r] * invr;
                op[32 + ql] = o1[r] * invr;
            }
            const int tokB = pw * 64 + 32 + row;
            if (tokB < NHIST) {
                float invr = __shfl(liB, row);
                float* op = out + ((size_t)bb * NTOK + tokB) * (HEADS * DHEAD) + hh * DHEAD;
                op[ql]      = o2[r] * invr;
                op[32 + ql] = o3[r] * invr;
            }
        }
    } else {
        const size_t pbase = ((size_t)bh * NSPLIT + sp) * MPATH;
        if (hi == 0) {
            if (q0 + ql < MPATH)      pl[pbase + q0 + ql]      = lAr;
            if (q0 + 32 + ql < MPATH) pl[pbase + q0 + 32 + ql] = lBr;
        }
        #pragma unroll
        for (int r = 0; r < 16; ++r) {
            const int row = (r & 3) + 8 * (r >> 2) + 4 * hi;
            const int qqA = q0 + row;
            if (qqA < MPATH) {
                float* pp = po + (pbase + qqA) * DHEAD;
                pp[ql]      = o0[r];
                pp[32 + ql] = o1[r];
            }
            const int qqB = q0 + 32 + row;
            if (qqB < MPATH) {
                float* pp = po + (pbase + qqB) * DHEAD;
                pp[ql]      = o2[r];
                pp[32 + ql] = o3[r];
            }
        }
    }
}

// ---------------- kernel 4: merge split-K partials (plain sums)
__global__ __launch_bounds__(256)
void combine_kernel(const float* __restrict__ pl, const float* __restrict__ po,
                    float* __restrict__ out)
{
    const int idx = blockIdx.x * 256 + threadIdx.x;
    const int dd  = idx & 63;
    const int r   = idx >> 6;
    if (r >= BATCH * HEADS * MPATH) return;
    const int bh = r / MPATH;
    const int jq = r - bh * MPATH;

    const size_t pbase = ((size_t)bh * NSPLIT) * MPATH + jq;
    float L = 0.f, acc = 0.f;
    #pragma unroll
    for (int s = 0; s < NSPLIT; ++s) {
        L   += pl[pbase + (size_t)s * MPATH];
        acc += po[(pbase + (size_t)s * MPATH) * DHEAD + dd];
    }
    const int bb = bh >> 3, hh = bh & 7;
    out[((size_t)bb * NTOK + (NHIST + jq)) * (HEADS * DHEAD) + hh * DHEAD + dd] = acc / L;
}

// ---------------- launcher ----------------
extern "C" void kernel_launch(void* const* d_in, const int* in_sizes, int n_in,
                              void* d_out, int out_size, void* d_ws, size_t ws_size,
                              hipStream_t stream)
{
    (void)in_sizes; (void)n_in; (void)out_size; (void)ws_size;
    const float* x = (const float*)d_in[0];
    const float* w = (const float*)d_in[1];
    float* out = (float*)d_out;

    const size_t QEL = (size_t)32 * NTOK * DHEAD + QPAD;   // tail pad for set-B over-read
    const size_t PEL = (size_t)32 * PROWS * DHEAD;
    const size_t HEL = (size_t)32 * HROWS * DHEAD;

    unsigned short* qb   = (unsigned short*)d_ws;
    unsigned short* kpth = qb   + QEL;
    unsigned short* khst = kpth + PEL;
    unsigned short* vtp  = khst + HEL;
    unsigned short* vth  = vtp  + PEL;
    unsigned short* xb   = vth  + HEL;
    unsigned short* wtb  = xb   + (size_t)MPAD * DIMIN;
    float* pl = (float*)(wtb + (size_t)QKVC * DIMIN);
    float* po = pl + (size_t)32 * NSPLIT * MPATH;

    prep_all<<<NB_CONV + NB_WT + NB_PAD, 256, 0, stream>>>(x, xb, w, wtb,
                                                           kpth, khst, vtp, vth);

    qkv_mfma<<<(MPAD / 128) * (QKVC / 128), 256, 0, stream>>>(xb, wtb, qb,
                                                              kpth, khst, vtp, vth);

    fused_attn<<<M1B + M0B, 256, 0, stream>>>(qb, kpth, khst, vtp, vth, out, pl, po);

    const int rows = BATCH * HEADS * MPATH;
    combine_kernel<<<(rows * DHEAD + 255) / 256, 256, 0, stream>>>(pl, po, out);
}

// Round 21
// 274.051 us; speedup vs baseline: 1.0698x; 1.0698x over previous
//
#include <hip/hip_runtime.h>
#include <hip/hip_bf16.h>

// ---------------- problem constants ----------------
#define BATCH  4
#define NTOK   12281
#define DIMIN  512
#define HEADS  8
#define DHEAD  64
#define MPATH  281
#define NHIST  12000               // NTOK - MPATH
#define QKVC   1536                // 3 * HEADS * DHEAD
#define QSCALE 0.180336884f        // DHEAD^-0.5 * log2(e)  (softmax uses exp2)
#define ROWS   (BATCH * NTOK)      // 49124
#define MPAD   49152               // 384 * 128 (padded GEMM M)
#define NSPLIT 16
#define KSPL   768                 // 24 tiles; splits 0-14 full, split 15 = 480 (15 tiles)
#define PROWS  320                 // padded path rows  (10 tiles of 32)
#define HROWS  12032               // padded hist rows  (376 tiles of 32)
#define M1B    640                 // MODE-1 blocks: 8 xcd x 80 (2 sp x 32 bh x 5 pw / 4)
#define M0B    1504                // MODE-0 blocks: 8 xcd x 4 g x 47
#define QPAD   4096                // qb tail pad (MODE0 set-B over-read, bh=31)
#define NB_CONV 12288              // MPAD*DIMIN/8/256
#define NB_WT   192                // (DIMIN/64)*(QKVC/64)
#define NB_PAD  312

typedef __attribute__((ext_vector_type(8)))  short        short8v;  // 8 bf16
typedef __attribute__((ext_vector_type(4)))  float        f32x4;
typedef __attribute__((ext_vector_type(16))) float        f32x16;
typedef __attribute__((ext_vector_type(4)))  unsigned int uint4v;

__device__ __forceinline__ unsigned short f2bf(float f) {          // RNE float->bf16
    unsigned x = __builtin_bit_cast(unsigned, f);
    return (unsigned short)((x + 0x7fffu + ((x >> 16) & 1u)) >> 16);
}
__device__ __forceinline__ unsigned pk2(float a, float b) {
    return (unsigned)f2bf(a) | ((unsigned)f2bf(b) << 16);
}
__device__ __forceinline__ unsigned pk2n(float a, float b) {       // native v_cvt_pk_bf16_f32
    unsigned r;
    asm("v_cvt_pk_bf16_f32 %0, %1, %2" : "=v"(r) : "v"(a), "v"(b));
    return r;
}
// v_permlane32_swap_b32: after, a = {a.lo, b.lo}, b = {a.hi, b.hi}
__device__ __forceinline__ void plswap(unsigned &a, unsigned &b) {
    asm("v_permlane32_swap_b32 %0, %1" : "+v"(a), "+v"(b));
}
__device__ __forceinline__ float fexp2(float x) {                  // v_exp_f32 (2^x)
    return __builtin_amdgcn_exp2f(x);
}
__device__ __forceinline__ short8v ld8(const unsigned short* p) {
    return *reinterpret_cast<const short8v*>(p);
}
__device__ __forceinline__ f32x16 MFMA32(short8v a, short8v b, f32x16 c) {
    return __builtin_amdgcn_mfma_f32_32x32x16_bf16(a, b, c, 0, 0, 0);
}
__device__ __forceinline__ void gl16(const char* g, char* l) {     // 16B global->LDS DMA
    __builtin_amdgcn_global_load_lds(
        (const __attribute__((address_space(1))) unsigned int*)g,
        (__attribute__((address_space(3))) unsigned int*)l, 16, 0, 0);
}

// ---------------- kernel P: merged prep (x->bf16, W->Wt bf16, pad zeroing)
__global__ __launch_bounds__(256)
void prep_all(const float* __restrict__ x, unsigned short* __restrict__ xb,
              const float* __restrict__ w, unsigned short* __restrict__ wt,
              unsigned short* kpth, unsigned short* vpth,
              unsigned short* khst, unsigned short* vhst)
{
    __shared__ unsigned short Ls[64][72];
    const int b   = blockIdx.x;
    const int tid = threadIdx.x;

    if (b < NB_CONV) {
        // ---- convert_x: fp32 -> bf16, rows padded to MPAD with zeros
        size_t i = ((size_t)b * 256 + tid) * 8;
        uint4v o;
        if (i < (size_t)ROWS * DIMIN) {
            float4 a = *reinterpret_cast<const float4*>(x + i);
            float4 c = *reinterpret_cast<const float4*>(x + i + 4);
            o[0] = pk2(a.x, a.y); o[1] = pk2(a.z, a.w);
            o[2] = pk2(c.x, c.y); o[3] = pk2(c.z, c.w);
        } else {
            o[0] = o[1] = o[2] = o[3] = 0u;
        }
        *reinterpret_cast<uint4v*>(xb + i) = o;
    } else if (b < NB_CONV + NB_WT) {
        // ---- wt_convert: W[512][1536] fp32 -> Wt[1536][512] bf16
        const int bb = b - NB_CONV;
        const int k0 = (bb & 7) * 64;
        const int n0 = (bb >> 3) * 64;
        const int lr = tid >> 2;
        const int c0 = (tid & 3) * 16;

        const float* sp = w + (size_t)(k0 + lr) * QKVC + n0 + c0;
        #pragma unroll
        for (int j = 0; j < 16; j += 4) {
            float4 a = *reinterpret_cast<const float4*>(sp + j);
            Ls[lr][c0 + j + 0] = f2bf(a.x);
            Ls[lr][c0 + j + 1] = f2bf(a.y);
            Ls[lr][c0 + j + 2] = f2bf(a.z);
            Ls[lr][c0 + j + 3] = f2bf(a.w);
        }
        __syncthreads();

        alignas(16) unsigned short tmp[16];
        #pragma unroll
        for (int j = 0; j < 16; ++j) tmp[j] = Ls[c0 + j][lr];
        unsigned short* dp = wt + (size_t)(n0 + lr) * DIMIN + k0 + c0;
        *reinterpret_cast<short8v*>(dp)     = *reinterpret_cast<short8v*>(&tmp[0]);
        *reinterpret_cast<short8v*>(dp + 8) = *reinterpret_cast<short8v*>(&tmp[8]);
    } else {
        // ---- pad_fill: zero the pad rows
        const int i = (b - NB_CONV - NB_WT) * 256 + tid;
        const int PPAD = (PROWS - MPATH) * DHEAD;
        const int HPAD = (HROWS - NHIST) * DHEAD;
        if (i < 32 * PPAD) {
            int bh = i / PPAD, r = i - bh * PPAD;
            size_t off = ((size_t)bh * PROWS + MPATH) * DHEAD + r;
            kpth[off] = 0; vpth[off] = 0;
        }
        if (i < 32 * HPAD) {
            int bh = i / HPAD, r = i - bh * HPAD;
            size_t off = ((size_t)bh * HROWS + NHIST) * DHEAD + r;
            khst[off] = 0; vhst[off] = 0;
        }
    }
}

// =====================================================================
// kernel 1: bf16 MFMA QKV GEMM. 128x128 tile, BK=64, 4 waves (2x2 of 64x64).
// Single 32KB stage buffer (m97 structure); epilogue reuses 34KB LDS;
// all global stores 16B coalesced (row-major V; transpose done separately
// -- r20's fused V^T scatter cost +46us in partial-line stores, reverted).
// =====================================================================
__global__ __launch_bounds__(256, 4)
void qkv_mfma(const unsigned short* __restrict__ xb, const unsigned short* __restrict__ wt,
              unsigned short* __restrict__ qb,
              unsigned short* __restrict__ kpth, unsigned short* __restrict__ khst,
              unsigned short* __restrict__ vpth, unsigned short* __restrict__ vhst)
{
    __shared__ char lds[34816];        // 32KB stage (16KB A + 16KB B) / 34KB epilogue
    const int tid  = threadIdx.x;
    const int lane = tid & 63;
    const int wid  = tid >> 6;
    const int wr   = wid >> 1;
    const int wc   = wid & 1;

    int id  = blockIdx.x;
    int wg  = (id & 7) * 576 + (id >> 3);
    const int mt = wg / 12, nt = wg - mt * 12;
    const int bm = mt * 128, bn = nt * 128;

    const int arow0 = tid >> 3;
    const int acolS = ((tid & 7) << 4) ^ ((arow0 & 7) << 4);
    const char* xsrc = (const char*)xb + (((size_t)(bm + arow0)) << 10) + acolS;
    const char* wsrc = (const char*)wt + (((size_t)(bn + arow0)) << 10) + acolS;
    char* ldsA = lds + wid * 1024;
    char* ldsB = lds + 16384 + wid * 1024;

    const int rA   = wr * 64 + (lane & 15);
    const int rB   = wc * 64 + (lane & 15);
    const int hi16 = (lane >> 4) << 4;
    const int sxA  = (rA & 7) << 4;
    const int sxB  = (rB & 7) << 4;

    f32x4 acc[4][4];
    #pragma unroll
    for (int m = 0; m < 4; ++m)
        #pragma unroll
        for (int n = 0; n < 4; ++n)
            #pragma unroll
            for (int r = 0; r < 4; ++r) acc[m][n][r] = 0.f;

    auto STAGE = [&](int ks) {
        const char* xs = xsrc + (size_t)ks * 128;
        const char* ws = wsrc + (size_t)ks * 128;
        #pragma unroll
        for (int i = 0; i < 4; ++i)
            gl16(xs + ((size_t)i << 15), ldsA + i * 4096);
        #pragma unroll
        for (int i = 0; i < 4; ++i)
            gl16(ws + ((size_t)i << 15), ldsB + i * 4096);
    };

    STAGE(0);
    asm volatile("s_waitcnt vmcnt(0)" ::: "memory");
    __syncthreads();

    for (int ks = 0; ks < 8; ++ks) {
        const char* A = lds;
        const char* B = A + 16384;
        #pragma unroll
        for (int kk = 0; kk < 2; ++kk) {
            short8v a[4], b[4];
            #pragma unroll
            for (int m = 0; m < 4; ++m)
                a[m] = *reinterpret_cast<const short8v*>(
                    A + (rA + m * 16) * 128 + ((kk * 64 + hi16) ^ sxA));
            #pragma unroll
            for (int n = 0; n < 4; ++n)
                b[n] = *reinterpret_cast<const short8v*>(
                    B + (rB + n * 16) * 128 + ((kk * 64 + hi16) ^ sxB));
            #pragma unroll
            for (int m = 0; m < 4; ++m)
                #pragma unroll
                for (int n = 0; n < 4; ++n)
                    acc[m][n] = __builtin_amdgcn_mfma_f32_16x16x32_bf16(
                        a[m], b[n], acc[m][n], 0, 0, 0);
        }
        __syncthreads();                 // all waves done reading the buffer
        if (ks < 7) {
            STAGE(ks + 1);
            asm volatile("s_waitcnt vmcnt(0)" ::: "memory");
            __syncthreads();
        }
    }

    unsigned short* cl = reinterpret_cast<unsigned short*>(lds);
    const int crow0 = (lane >> 4) * 4;
    const int ccol  = lane & 15;
    #pragma unroll
    for (int n = 0; n < 4; ++n) {
        const int gcb = bn + wc * 64 + n * 16;
        const float scl = (gcb < 512) ? QSCALE : 1.f;
        #pragma unroll
        for (int m = 0; m < 4; ++m) {
            #pragma unroll
            for (int r = 0; r < 4; ++r) {
                int row = wr * 64 + m * 16 + crow0 + r;
                int col = wc * 64 + n * 16 + ccol;
                cl[row * 136 + col] = f2bf(acc[m][n][r] * scl);
            }
        }
    }
    __syncthreads();

    #pragma unroll
    for (int i = 0; i < 8; ++i) {
        const int chunk = tid + i * 256;
        const int row = chunk >> 4;
        const int c8  = (chunk & 15) * 8;
        const int grow = bm + row;
        if (grow < ROWS) {
            uint4v val = *reinterpret_cast<const uint4v*>(cl + row * 136 + c8);
            const int gcol  = bn + c8;
            const int which = gcol >> 9;
            const int rem   = gcol & 511;
            const int hh = rem >> 6, dd = rem & 63;
            const int bb = grow / NTOK;
            const int nn = grow - bb * NTOK;
            const int bh = bb * HEADS + hh;
            unsigned short* dst;
            if (which == 0) {
                dst = qb + ((size_t)bh * NTOK + nn) * DHEAD + dd;
            } else if (which == 1) {
                dst = (nn < MPATH) ? kpth + ((size_t)bh * PROWS + nn) * DHEAD + dd
                                   : khst + ((size_t)bh * HROWS + (nn - MPATH)) * DHEAD + dd;
            } else {
                dst = (nn < MPATH) ? vpth + ((size_t)bh * PROWS + nn) * DHEAD + dd
                                   : vhst + ((size_t)bh * HROWS + (nn - MPATH)) * DHEAD + dd;
            }
            *reinterpret_cast<uint4v*>(dst) = val;
        }
    }
}

// ---------------- kernel 2: merged transpose to TILE-BLOCKED V^T
// path (bx<5) and hist (bx>=5) in one launch
__global__ __launch_bounds__(256)
void transpose_both(const unsigned short* __restrict__ vpth, unsigned short* __restrict__ vtp,
                    const unsigned short* __restrict__ vhst, unsigned short* __restrict__ vth)
{
    __shared__ unsigned short Ls[64][72];
    const int bh = blockIdx.y;
    const unsigned short* s;
    unsigned short* d;
    int r0;
    if (blockIdx.x < PROWS / 64) {
        r0 = blockIdx.x * 64;
        s  = vpth + (size_t)bh * PROWS * DHEAD;
        d  = vtp  + (size_t)bh * PROWS * DHEAD;
    } else {
        r0 = (blockIdx.x - PROWS / 64) * 64;
        s  = vhst + (size_t)bh * HROWS * DHEAD;
        d  = vth  + (size_t)bh * HROWS * DHEAD;
    }

    const int t  = threadIdx.x;
    const int lr = t >> 2;          // 0..63
    const int c0 = (t & 3) * 16;    // 0,16,32,48

    const unsigned short* sp = s + (size_t)(r0 + lr) * DHEAD + c0;
    *reinterpret_cast<short8v*>(&Ls[lr][c0])     = *reinterpret_cast<const short8v*>(sp);
    *reinterpret_cast<short8v*>(&Ls[lr][c0 + 8]) = *reinterpret_cast<const short8v*>(sp + 8);
    __syncthreads();

    alignas(16) unsigned short tmp[16];
    #pragma unroll
    for (int j = 0; j < 16; ++j) tmp[j] = Ls[c0 + j][lr];
    const int T  = (r0 + c0) >> 5;
    const int kk = (r0 + c0) & 31;
    unsigned short* dp = d + (((size_t)T * 64 + lr) << 5) + kk;
    *reinterpret_cast<short8v*>(dp)     = *reinterpret_cast<short8v*>(&tmp[0]);
    *reinterpret_cast<short8v*>(dp + 8) = *reinterpret_cast<short8v*>(&tmp[8]);
}

// ---- attention tile body (r16/r19 configuration: the ~120us best).
// VC* = V(t) (consumed); VN* = V(t+1) prefetch AFTER PV; K reload after QK.
#define ATTN_BODY(VC0,VC1,VC2,VC3,VN0,VN1,VN2,VN3,TT)                      \
  do {                                                                     \
    __builtin_amdgcn_s_setprio(1);                                         \
    f32x16 sA = MFMA32(kf0, qA0, SZ);                                      \
    sA = MFMA32(kf1, qA1, sA);                                             \
    sA = MFMA32(kf2, qA2, sA);                                             \
    sA = MFMA32(kf3, qA3, sA);                                             \
    f32x16 sB = MFMA32(kf0, qB0, SZ);                                      \
    sB = MFMA32(kf1, qB1, sB);                                             \
    sB = MFMA32(kf2, qB2, sB);                                             \
    sB = MFMA32(kf3, qB3, sB);                                             \
    __builtin_amdgcn_s_setprio(0);                                         \
    if ((TT) + 1 < ntiles) {   /* K(t+1) reload after QK consumed kf */    \
      const unsigned short* kn = kr + (size_t)((TT) + 1) * 2048;           \
      kf0 = ld8(kn);      kf1 = ld8(kn + 16);                              \
      kf2 = ld8(kn + 32); kf3 = ld8(kn + 48);                              \
    }                                                                      \
    float psA = 0.f, psB = 0.f;                                            \
    if (mode0 && (TT) == 8) {          /* mask path keys >= 281 */         \
      _Pragma("unroll")                                                    \
      for (int r = 0; r < 16; ++r) {                                       \
        int krow = (r & 3) + 8 * (r >> 2) + 4 * hi;                        \
        float eA = (256 + krow >= MPATH) ? 0.f : fexp2(sA[r]);             \
        float eB = (256 + krow >= MPATH) ? 0.f : fexp2(sB[r]);             \
        sA[r] = eA; psA += eA;                                             \
        sB[r] = eB; psB += eB;                                             \
      }                                                                    \
    } else {                                                               \
      _Pragma("unroll")                                                    \
      for (int r = 0; r < 16; ++r) {                                       \
        float eA = fexp2(sA[r]); sA[r] = eA; psA += eA;                    \
        float eB = fexp2(sB[r]); sB[r] = eB; psB += eB;                    \
      }                                                                    \
    }                                                                      \
    lA += psA; lB += psB;                                                  \
    unsigned A0 = pk2n(sA[0],  sA[1]),  A1 = pk2n(sA[2],  sA[3]);          \
    unsigned A2 = pk2n(sA[4],  sA[5]),  A3 = pk2n(sA[6],  sA[7]);          \
    unsigned A4 = pk2n(sA[8],  sA[9]),  A5 = pk2n(sA[10], sA[11]);         \
    unsigned A6 = pk2n(sA[12], sA[13]), A7 = pk2n(sA[14], sA[15]);         \
    plswap(A0, A2); plswap(A1, A3); plswap(A4, A6); plswap(A5, A7);        \
    uint4v wA0, wA1;                                                       \
    wA0[0] = A0; wA0[1] = A1; wA0[2] = A2; wA0[3] = A3;                    \
    wA1[0] = A4; wA1[1] = A5; wA1[2] = A6; wA1[3] = A7;                    \
    short8v paA0 = __builtin_bit_cast(short8v, wA0);                       \
    short8v paA1 = __builtin_bit_cast(short8v, wA1);                       \
    unsigned B0 = pk2n(sB[0],  sB[1]),  B1 = pk2n(sB[2],  sB[3]);          \
    unsigned B2 = pk2n(sB[4],  sB[5]),  B3 = pk2n(sB[6],  sB[7]);          \
    unsigned B4 = pk2n(sB[8],  sB[9]),  B5 = pk2n(sB[10], sB[11]);         \
    unsigned B6 = pk2n(sB[12], sB[13]), B7 = pk2n(sB[14], sB[15]);         \
    plswap(B0, B2); plswap(B1, B3); plswap(B4, B6); plswap(B5, B7);        \
    uint4v wB0, wB1;                                                       \
    wB0[0] = B0; wB0[1] = B1; wB0[2] = B2; wB0[3] = B3;                    \
    wB1[0] = B4; wB1[1] = B5; wB1[2] = B6; wB1[3] = B7;                    \
    short8v paB0 = __builtin_bit_cast(short8v, wB0);                       \
    short8v paB1 = __builtin_bit_cast(short8v, wB1);                       \
    __builtin_amdgcn_s_setprio(1);                                         \
    o0 = MFMA32(paA0, VC0, o0);                                            \
    o0 = MFMA32(paA1, VC1, o0);                                            \
    o1 = MFMA32(paA0, VC2, o1);                                            \
    o1 = MFMA32(paA1, VC3, o1);                                            \
    o2 = MFMA32(paB0, VC0, o2);                                            \
    o2 = MFMA32(paB1, VC1, o2);                                            \
    o3 = MFMA32(paB0, VC2, o3);                                            \
    o3 = MFMA32(paB1, VC3, o3);                                            \
    __builtin_amdgcn_s_setprio(0);                                         \
    if ((TT) + 1 < ntiles) {   /* load V(t+1) */                           \
      const unsigned short* vn = vbase + (size_t)((TT) + 1) * 2048;        \
      VN0 = ld8(vn);        VN1 = ld8(vn + 16);                            \
      VN2 = ld8(vn + 1024); VN3 = ld8(vn + 1040);                          \
    }                                                                      \
  } while (0)

// =====================================================================
// kernel 3: FUSED MFMA flash attention, 64 queries/wave (two S-tiles per
// K/V load set), K(t+1) AND V(t+1) register-prefetched a full tile ahead.
// Blocks [0, M1B):       MODE 1 (path q x hist k), XCD-pinned by sp%8
// Blocks [M1B, M1B+M0B): MODE 0 (hist q x path k), XCD-pinned by bh group
// =====================================================================
__global__ __launch_bounds__(256, 2)
void fused_attn(const unsigned short* __restrict__ qbuf,
                const unsigned short* __restrict__ kpth, const unsigned short* __restrict__ khst,
                const unsigned short* __restrict__ vtp,  const unsigned short* __restrict__ vth,
                float* __restrict__ out,
                float* __restrict__ pl, float* __restrict__ po)
{
    const int wave = threadIdx.x >> 6;
    const int lane = threadIdx.x & 63;
    const int hi   = lane >> 5;
    const int ql   = lane & 31;

    int bh, pw, sp = 0;
    bool mode0;
    if (blockIdx.x < M1B) {
        mode0 = false;
        const int xcd = blockIdx.x & 7;
        const int j   = blockIdx.x >> 3;         // 0..79
        const int w   = j * 4 + wave;            // 0..319
        const int spi = w / 160;                 // 0..1
        const int rem = w - spi * 160;
        bh = rem / 5;                            // 0..31
        pw = rem - bh * 5;                       // 0..4
        sp = xcd + 8 * spi;                      // pinned to xcd mod 8
    } else {
        mode0 = true;
        const int b0  = blockIdx.x - M1B;
        const int xcd = b0 & 7;
        const int i   = b0 >> 3;                 // 0..187
        const int g   = i / 47;                  // 0..3
        bh = xcd + 8 * g;
        pw = (i - g * 47) * 4 + wave;            // 0..187 (exactly covered)
    }

    const int q0 = mode0 ? (MPATH + pw * 64) : (pw * 64);
    const unsigned short* qra = qbuf + ((size_t)bh * NTOK + (q0 + ql)) * DHEAD + hi * 8;
    const unsigned short* qrb = qra + (size_t)32 * DHEAD;
    short8v qA0 = ld8(qra),      qA1 = ld8(qra + 16);
    short8v qA2 = ld8(qra + 32), qA3 = ld8(qra + 48);
    short8v qB0 = ld8(qrb),      qB1 = ld8(qrb + 16);
    short8v qB2 = ld8(qrb + 32), qB3 = ld8(qrb + 48);

    const unsigned short* kr;        // lane-adjusted K base (tile stride 2048)
    const unsigned short* vbase;     // lane-adjusted tile-blocked V^T base
    int ntiles;
    if (mode0) {
        kr    = kpth + (size_t)bh * PROWS * DHEAD + ql * DHEAD + hi * 8;
        vbase = vtp  + (size_t)bh * PROWS * DHEAD + ql * 32 + hi * 8;
        ntiles = 9;
    } else {
        kr    = khst + ((size_t)bh * HROWS + (size_t)sp * KSPL) * DHEAD + ql * DHEAD + hi * 8;
        vbase = vth  + (size_t)bh * HROWS * DHEAD + (size_t)sp * 24 * 2048 + ql * 32 + hi * 8;
        ntiles = (sp == NSPLIT - 1) ? 15 : 24;   // split 15: 480 keys exactly
    }

    f32x16 o0, o1, o2, o3, SZ;
    #pragma unroll
    for (int r = 0; r < 16; ++r) { o0[r] = 0.f; o1[r] = 0.f; o2[r] = 0.f; o3[r] = 0.f; SZ[r] = 0.f; }
    float lA = 0.f, lB = 0.f;

    // prologue: K(0), V(0)
    short8v kf0 = ld8(kr), kf1 = ld8(kr + 16), kf2 = ld8(kr + 32), kf3 = ld8(kr + 48);
    short8v va0 = ld8(vbase),        va1 = ld8(vbase + 16);
    short8v va2 = ld8(vbase + 1024), va3 = ld8(vbase + 1040);
    short8v vb0 = va0, vb1 = va1, vb2 = va2, vb3 = va3;   // init (dead unless rotated)

    for (int t = 0;;) {
        ATTN_BODY(va0, va1, va2, va3, vb0, vb1, vb2, vb3, t);
        if (++t >= ntiles) break;
        ATTN_BODY(vb0, vb1, vb2, vb3, va0, va1, va2, va3, t);
        if (++t >= ntiles) break;
    }

    const float lAr = lA + __shfl_xor(lA, 32);
    const float lBr = lB + __shfl_xor(lB, 32);

    if (mode0) {
        const int bb = bh >> 3, hh = bh & 7;
        const float liA = 1.0f / lAr;
        const float liB = 1.0f / lBr;
        #pragma unroll
        for (int r = 0; r < 16; ++r) {
            const int row = (r & 3) + 8 * (r >> 2) + 4 * hi;
            {
                float invr = __shfl(liA, row);
                float* op = out + ((size_t)bb * NTOK + (pw * 64 + row)) * (HEADS * DHEAD) + hh * DHEAD;
                op[ql]      = o0[r] * invr;
                op[32 + ql] = o1[r] * invr;
            }
            const int tokB = pw * 64 + 32 + row;
            if (tokB < NHIST) {
                float invr = __shfl(liB, row);
                float* op = out + ((size_t)bb * NTOK + tokB) * (HEADS * DHEAD) + hh * DHEAD;
                op[ql]      = o2[r] * invr;
                op[32 + ql] = o3[r] * invr;
            }
        }
    } else {
        const size_t pbase = ((size_t)bh * NSPLIT + sp) * MPATH;
        if (hi == 0) {
            if (q0 + ql < MPATH)      pl[pbase + q0 + ql]      = lAr;
            if (q0 + 32 + ql < MPATH) pl[pbase + q0 + 32 + ql] = lBr;
        }
        #pragma unroll
        for (int r = 0; r < 16; ++r) {
            const int row = (r & 3) + 8 * (r >> 2) + 4 * hi;
            const int qqA = q0 + row;
            if (qqA < MPATH) {
                float* pp = po + (pbase + qqA) * DHEAD;
                pp[ql]      = o0[r];
                pp[32 + ql] = o1[r];
            }
            const int qqB = q0 + 32 + row;
            if (qqB < MPATH) {
                float* pp = po + (pbase + qqB) * DHEAD;
                pp[ql]      = o2[r];
                pp[32 + ql] = o3[r];
            }
        }
    }
}

// ---------------- kernel 4: merge split-K partials (plain sums)
__global__ __launch_bounds__(256)
void combine_kernel(const float* __restrict__ pl, const float* __restrict__ po,
                    float* __restrict__ out)
{
    const int idx = blockIdx.x * 256 + threadIdx.x;
    const int dd  = idx & 63;
    const int r   = idx >> 6;
    if (r >= BATCH * HEADS * MPATH) return;
    const int bh = r / MPATH;
    const int jq = r - bh * MPATH;

    const size_t pbase = ((size_t)bh * NSPLIT) * MPATH + jq;
    float L = 0.f, acc = 0.f;
    #pragma unroll
    for (int s = 0; s < NSPLIT; ++s) {
        L   += pl[pbase + (size_t)s * MPATH];
        acc += po[(pbase + (size_t)s * MPATH) * DHEAD + dd];
    }
    const int bb = bh >> 3, hh = bh & 7;
    out[((size_t)bb * NTOK + (NHIST + jq)) * (HEADS * DHEAD) + hh * DHEAD + dd] = acc / L;
}

// ---------------- launcher ----------------
extern "C" void kernel_launch(void* const* d_in, const int* in_sizes, int n_in,
                              void* d_out, int out_size, void* d_ws, size_t ws_size,
                              hipStream_t stream)
{
    (void)in_sizes; (void)n_in; (void)out_size; (void)ws_size;
    const float* x = (const float*)d_in[0];
    const float* w = (const float*)d_in[1];
    float* out = (float*)d_out;

    const size_t QEL = (size_t)32 * NTOK * DHEAD + QPAD;   // tail pad for set-B over-read
    const size_t PEL = (size_t)32 * PROWS * DHEAD;
    const size_t HEL = (size_t)32 * HROWS * DHEAD;

    unsigned short* qb   = (unsigned short*)d_ws;
    unsigned short* kpth = qb   + QEL;
    unsigned short* khst = kpth + PEL;
    unsigned short* vpth = khst + HEL;
    unsigned short* vhst = vpth + PEL;
    unsigned short* vtp  = vhst + HEL;
    unsigned short* vth  = vtp  + PEL;
    unsigned short* xb   = vth  + HEL;
    unsigned short* wtb  = xb   + (size_t)MPAD * DIMIN;
    float* pl = (float*)(wtb + (size_t)QKVC * DIMIN);
    float* po = pl + (size_t)32 * NSPLIT * MPATH;

    prep_all<<<NB_CONV + NB_WT + NB_PAD, 256, 0, stream>>>(x, xb, w, wtb,
                                                           kpth, vpth, khst, vhst);

    qkv_mfma<<<(MPAD / 128) * (QKVC / 128), 256, 0, stream>>>(xb, wtb, qb,
                                                              kpth, khst, vpth, vhst);

    transpose_both<<<dim3(PROWS / 64 + HROWS / 64, 32), 256, 0, stream>>>(vpth, vtp,
                                                                          vhst, vth);

    fused_attn<<<M1B + M0B, 256, 0, stream>>>(qb, kpth, khst, vtp, vth, out, pl, po);

    const int rows = BATCH * HEADS * MPATH;
    combine_kernel<<<(rows * DHEAD + 255) / 256, 256, 0, stream>>>(pl, po, out);
}